// Round 1
// baseline (2226.058 us; speedup 1.0000x reference)
//
#include <hip/hip_runtime.h>
#include <stdint.h>

#define T_STEPS 128
#define BATCH   64
#define EMBED   256
#define HIDDEN  512
#define VOCAB   10000
#define M_ROWS  (T_STEPS*BATCH)   // 8192
#define NGATE   (4*HIDDEN)        // 2048

typedef __attribute__((ext_vector_type(4))) float  f32x4;
typedef __attribute__((ext_vector_type(4))) int    i32x4;
typedef __attribute__((ext_vector_type(8))) __bf16 bf16x8;

static __device__ __forceinline__ unsigned short f32_to_bf16(float f) {
    union { float f; uint32_t u; } v; v.f = f;
    uint32_t u = v.u;
    return (unsigned short)((u + 0x7FFFu + ((u >> 16) & 1u)) >> 16);  // RNE
}

// ---------------------------------------------------------------------------
// W [512][10000] f32  ->  Wt [10000][512] bf16   (tiled transpose + convert)
// ---------------------------------------------------------------------------
__global__ void wt_convert(const float* __restrict__ W, unsigned short* __restrict__ Wt) {
    __shared__ float tile[32][33];
    int n0 = blockIdx.x * 32;
    int k0 = blockIdx.y * 32;
    int tx = threadIdx.x, ty = threadIdx.y;
    int n = n0 + tx;
    if (n < VOCAB) tile[ty][tx] = W[(size_t)(k0 + ty) * VOCAB + n];
    __syncthreads();
    int nn = n0 + ty;
    if (nn < VOCAB) Wt[(size_t)nn * HIDDEN + k0 + tx] = f32_to_bf16(tile[tx][ty]);
}

// ---------------------------------------------------------------------------
// xg[m][g*512+hc] = embeddings[input_[m]] @ W_xg + b_g   (fp32 tiled GEMM,
// gather fused).  M=8192, N=2048, K=256.  BM=128 BN=64 BK=32, 256 thr.
// ---------------------------------------------------------------------------
__global__ __launch_bounds__(256) void xproj(
    const int* __restrict__ idx, const float* __restrict__ Emb,
    const float* __restrict__ Wxi, const float* __restrict__ Wxf,
    const float* __restrict__ Wxc, const float* __restrict__ Wxo,
    const float* __restrict__ bi,  const float* __restrict__ bf_,
    const float* __restrict__ bc,  const float* __restrict__ bo,
    float* __restrict__ xg)
{
    __shared__ float At[32][132];   // [k][m], padded
    __shared__ float Bt[32][68];    // [k][n], padded
    int cb = blockIdx.x;            // 0..31 (8 col-blocks per gate)
    int rb = blockIdx.y;            // 0..63
    int g  = cb >> 3;
    int hc0 = (cb & 7) * 64;
    const float* Wg = (g == 0) ? Wxi : (g == 1) ? Wxf : (g == 2) ? Wxc : Wxo;
    const float* bg = (g == 0) ? bi  : (g == 1) ? bf_ : (g == 2) ? bc  : bo;
    int m0 = rb * 128;
    int tid = threadIdx.x;
    int tr = tid >> 4, tc = tid & 15;
    float acc[8][4] = {};

    for (int kc = 0; kc < EMBED; kc += 32) {
        // stage A (gathered embedding rows), transposed into At[k][m]
        #pragma unroll
        for (int i = 0; i < 4; ++i) {
            int s = tid + i * 256;            // 0..1023
            int row = s >> 3, k4 = s & 7;
            int er = idx[m0 + row];
            f32x4 v = *reinterpret_cast<const f32x4*>(Emb + (size_t)er * EMBED + kc + k4 * 4);
            #pragma unroll
            for (int j = 0; j < 4; ++j) At[k4 * 4 + j][row] = v[j];
        }
        // stage B
        #pragma unroll
        for (int i = 0; i < 2; ++i) {
            int s = tid + i * 256;            // 0..511
            int k = s >> 4, c4 = s & 15;
            f32x4 v = *reinterpret_cast<const f32x4*>(Wg + (size_t)(kc + k) * HIDDEN + hc0 + c4 * 4);
            *reinterpret_cast<f32x4*>(&Bt[k][c4 * 4]) = v;
        }
        __syncthreads();
        #pragma unroll 8
        for (int k = 0; k < 32; ++k) {
            f32x4 a0 = *reinterpret_cast<const f32x4*>(&At[k][tr * 8]);
            f32x4 a1 = *reinterpret_cast<const f32x4*>(&At[k][tr * 8 + 4]);
            f32x4 b4 = *reinterpret_cast<const f32x4*>(&Bt[k][tc * 4]);
            float av[8] = {a0[0],a0[1],a0[2],a0[3],a1[0],a1[1],a1[2],a1[3]};
            #pragma unroll
            for (int i = 0; i < 8; ++i)
                #pragma unroll
                for (int j = 0; j < 4; ++j)
                    acc[i][j] += av[i] * b4[j];
        }
        __syncthreads();
    }
    f32x4 bb = *reinterpret_cast<const f32x4*>(bg + hc0 + tc * 4);
    #pragma unroll
    for (int i = 0; i < 8; ++i) {
        int row = m0 + tr * 8 + i;
        f32x4 o;
        #pragma unroll
        for (int j = 0; j < 4; ++j) o[j] = acc[i][j] + bb[j];
        *reinterpret_cast<f32x4*>(xg + (size_t)row * NGATE + g * HIDDEN + hc0 + tc * 4) = o;
    }
}

// ---------------------------------------------------------------------------
// One LSTM step.  256 blocks: (8 b) x (16 hc) x (K split in halves inside
// block).  thread = (b,hc,khalf), 4 gate-dots of K=256 each; LDS combine,
// then fused activations + cell update.
// ---------------------------------------------------------------------------
__global__ __launch_bounds__(256) void lstm_step(
    const float* __restrict__ xg,
    const float* __restrict__ Whi, const float* __restrict__ Whf,
    const float* __restrict__ Whc, const float* __restrict__ Who,
    float* __restrict__ hs, unsigned short* __restrict__ hsbf,
    float* __restrict__ c, int t)
{
    __shared__ float H[8][520];     // h rows for this block's 8 b's (padded)
    __shared__ float P[256][4];     // per-thread partials
    int tid = threadIdx.x;
    int hcl = tid & 15, bl = (tid >> 4) & 7, kh = tid >> 7;
    int bx = blockIdx.x;
    int b0 = (bx >> 5) * 8, hc0 = (bx & 31) * 16;

    float p0 = 0.f, p1 = 0.f, p2 = 0.f, p3 = 0.f;
    if (t > 0) {
        const float* hprev = hs + (size_t)(t - 1) * BATCH * HIDDEN;
        #pragma unroll
        for (int i = 0; i < 4; ++i) {
            int s = tid + i * 256;          // 8 rows x 128 float4
            int row = s >> 7, k4 = s & 127;
            f32x4 v = *reinterpret_cast<const f32x4*>(hprev + (size_t)(b0 + row) * HIDDEN + k4 * 4);
            *reinterpret_cast<f32x4*>(&H[row][k4 * 4]) = v;
        }
        __syncthreads();
        int kbase = kh * 256;
        int woff = kbase * HIDDEN + hc0 + hcl;
        #pragma unroll 8
        for (int k = 0; k < 256; ++k) {
            float hv = H[bl][kbase + k];
            p0 += hv * Whi[woff];
            p1 += hv * Whf[woff];
            p2 += hv * Whc[woff];
            p3 += hv * Who[woff];
            woff += HIDDEN;
        }
    }
    P[tid][0] = p0; P[tid][1] = p1; P[tid][2] = p2; P[tid][3] = p3;
    __syncthreads();

    if (tid < 128) {
        int hcl2 = tid & 15, bl2 = (tid >> 4) & 7;
        int b = b0 + bl2, hc = hc0 + hcl2;
        const float* xrow = xg + (size_t)(t * BATCH + b) * NGATE;
        float pi = P[tid][0] + P[tid + 128][0] + xrow[0 * HIDDEN + hc];
        float pf = P[tid][1] + P[tid + 128][1] + xrow[1 * HIDDEN + hc];
        float pg = P[tid][2] + P[tid + 128][2] + xrow[2 * HIDDEN + hc];
        float po = P[tid][3] + P[tid + 128][3] + xrow[3 * HIDDEN + hc];
        float i_ = 1.f / (1.f + __expf(-pi));
        float f_ = 1.f / (1.f + __expf(-pf));
        float eg = __expf(2.f * fminf(fmaxf(pg, -15.f), 15.f));
        float g_ = (eg - 1.f) / (eg + 1.f);
        float o_ = 1.f / (1.f + __expf(-po));
        float cold = (t > 0) ? c[(size_t)b * HIDDEN + hc] : 0.f;
        float cn = f_ * cold + i_ * g_;
        float ec = __expf(2.f * fminf(fmaxf(cn, -15.f), 15.f));
        float th = (ec - 1.f) / (ec + 1.f);
        float h = o_ * th;
        c[(size_t)b * HIDDEN + hc] = cn;
        hs[(size_t)(t * BATCH + b) * HIDDEN + hc] = h;
        hsbf[(size_t)(t * BATCH + b) * HIDDEN + hc] = f32_to_bf16(h);
    }
}

// ---------------------------------------------------------------------------
// out = hs_bf16 [8192,512] @ W_bf16^T [10000,512] + b   (bf16 MFMA, f32 acc)
// tile 128x80, BK=64, 4 waves, acc[2][5], XOR-swizzled LDS (T2).
// ---------------------------------------------------------------------------
__global__ __launch_bounds__(256) void out_proj(
    const unsigned short* __restrict__ Abf,   // [8192][512]
    const unsigned short* __restrict__ Btbf,  // [10000][512]
    const float* __restrict__ bias,           // [10000]
    float* __restrict__ Cout)                 // [8192][10000] f32
{
    __shared__ __align__(16) char sA[128 * 128];  // 128 rows x 64 bf16
    __shared__ __align__(16) char sB[80 * 128];   // 80 rows x 64 bf16
    int n0 = blockIdx.x * 80;
    int m0 = blockIdx.y * 128;
    int tid = threadIdx.x;
    int w = tid >> 6, lane = tid & 63;
    f32x4 acc[2][5] = {};

    for (int kc = 0; kc < 8; ++kc) {
        int k0 = kc * 64;
        #pragma unroll
        for (int i = 0; i < 4; ++i) {                  // A: 1024 16B slots
            int s = tid + i * 256;
            int row = s >> 3, slot = s & 7;
            i32x4 v = *reinterpret_cast<const i32x4*>(Abf + (size_t)(m0 + row) * HIDDEN + k0 + slot * 8);
            *reinterpret_cast<i32x4*>(sA + row * 128 + ((slot ^ (row & 7)) * 16)) = v;
        }
        #pragma unroll
        for (int i = 0; i < 3; ++i) {                  // B: 640 slots
            int s = tid + i * 256;
            if (s < 640) {
                int row = s >> 3, slot = s & 7;
                i32x4 v = *reinterpret_cast<const i32x4*>(Btbf + (size_t)(n0 + row) * HIDDEN + k0 + slot * 8);
                *reinterpret_cast<i32x4*>(sB + row * 128 + ((slot ^ (row & 7)) * 16)) = v;
            }
        }
        __syncthreads();
        #pragma unroll
        for (int k2 = 0; k2 < 2; ++k2) {
            bf16x8 a[2], b[5];
            #pragma unroll
            for (int rf = 0; rf < 2; ++rf) {
                int row = w * 32 + rf * 16 + (lane & 15);
                int off = (k2 * 64 + (lane >> 4) * 16) ^ ((row & 7) << 4);
                a[rf] = *reinterpret_cast<const bf16x8*>(sA + row * 128 + off);
            }
            #pragma unroll
            for (int cf = 0; cf < 5; ++cf) {
                int row = cf * 16 + (lane & 15);
                int off = (k2 * 64 + (lane >> 4) * 16) ^ ((row & 7) << 4);
                b[cf] = *reinterpret_cast<const bf16x8*>(sB + row * 128 + off);
            }
            #pragma unroll
            for (int rf = 0; rf < 2; ++rf)
                #pragma unroll
                for (int cf = 0; cf < 5; ++cf)
                    acc[rf][cf] = __builtin_amdgcn_mfma_f32_16x16x32_bf16(a[rf], b[cf], acc[rf][cf], 0, 0, 0);
        }
        __syncthreads();
    }
    #pragma unroll
    for (int cf = 0; cf < 5; ++cf) {
        int col = n0 + cf * 16 + (lane & 15);
        float bv = bias[col];
        #pragma unroll
        for (int rf = 0; rf < 2; ++rf)
            #pragma unroll
            for (int r = 0; r < 4; ++r) {
                int row = m0 + w * 32 + rf * 16 + (lane >> 4) * 4 + r;
                Cout[(size_t)row * VOCAB + col] = acc[rf][cf][r] + bv;
            }
    }
}

// ---------------------------------------------------------------------------
__global__ void finalize_hc(const float* __restrict__ hs, const float* __restrict__ c,
                            float* __restrict__ out) {
    int i = blockIdx.x * 256 + threadIdx.x;       // 0..65535
    size_t base = (size_t)M_ROWS * VOCAB;
    if (i < BATCH * HIDDEN)
        out[base + i] = hs[(size_t)(T_STEPS - 1) * BATCH * HIDDEN + i];
    else
        out[base + i] = c[i - BATCH * HIDDEN];
}

extern "C" void kernel_launch(void* const* d_in, const int* in_sizes, int n_in,
                              void* d_out, int out_size, void* d_ws, size_t ws_size,
                              hipStream_t stream) {
    (void)in_sizes; (void)n_in; (void)out_size; (void)ws_size;
    const int*   input_ = (const int*)  d_in[0];
    const float* Emb    = (const float*)d_in[1];
    const float* Wxi    = (const float*)d_in[2];
    const float* Whi    = (const float*)d_in[3];
    const float* bi     = (const float*)d_in[4];
    const float* Wxf    = (const float*)d_in[5];
    const float* Whf    = (const float*)d_in[6];
    const float* bf_    = (const float*)d_in[7];
    const float* Wxc    = (const float*)d_in[8];
    const float* Whc    = (const float*)d_in[9];
    const float* bc     = (const float*)d_in[10];
    const float* Wxo    = (const float*)d_in[11];
    const float* Who    = (const float*)d_in[12];
    const float* bo     = (const float*)d_in[13];
    const float* W      = (const float*)d_in[14];
    const float* b      = (const float*)d_in[15];
    float* out = (float*)d_out;

    char* ws = (char*)d_ws;
    float*          xg   = (float*)         (ws);                    //  67,108,864 B
    float*          hs   = (float*)         (ws +  67108864);        //  16,777,216 B
    unsigned short* hsbf = (unsigned short*)(ws +  83886080);        //   8,388,608 B
    unsigned short* Wtbf = (unsigned short*)(ws +  92274688);        //  10,240,000 B
    float*          cbuf = (float*)         (ws + 102514688);        //     131,072 B

    wt_convert<<<dim3(313, 16), dim3(32, 32), 0, stream>>>(W, Wtbf);
    xproj<<<dim3(32, 64), 256, 0, stream>>>(input_, Emb, Wxi, Wxf, Wxc, Wxo,
                                            bi, bf_, bc, bo, xg);
    for (int t = 0; t < T_STEPS; ++t)
        lstm_step<<<256, 256, 0, stream>>>(xg, Whi, Whf, Whc, Who, hs, hsbf, cbuf, t);
    out_proj<<<dim3(125, 64), 256, 0, stream>>>(hsbf, Wtbf, b, out);
    finalize_hc<<<256, 256, 0, stream>>>(hs, cbuf, out);
}